// Round 2
// baseline (638.547 us; speedup 1.0000x reference)
//
#include <hip/hip_runtime.h>
#include <hip/hip_bf16.h>

#define N_UTT 4000
#define NDIM 256
#define B_DIA 100
#define L_DIA 40
#define NNODE 12000   // 3*N_UTT
#define NLAYERS 4

typedef __attribute__((ext_vector_type(8))) short short8;   // 8 bf16 (4 VGPRs)
typedef __attribute__((ext_vector_type(4))) float f32x4;    // MFMA acc

// ---------------------------------------------------------------------------
// K1: build x = concat(a, v, l + spk_emb[argmax(q)]), invn, x_bf16, xn_bf16
// one block (256 thr) per node row
__global__ void k_build_x(const float* __restrict__ a, const float* __restrict__ v,
                          const float* __restrict__ l, const float* __restrict__ qmask,
                          const float* __restrict__ spk, float* __restrict__ x,
                          float* __restrict__ invn,
                          __hip_bfloat16* __restrict__ xb,
                          __hip_bfloat16* __restrict__ xnb) {
  int r = blockIdx.x;          // 0..11999
  int t = threadIdx.x;         // 0..255
  int m = r / N_UTT;
  int i = r - m * N_UTT;
  float val;
  if (m == 0) val = a[i * NDIM + t];
  else if (m == 1) val = v[i * NDIM + t];
  else {
    int b = i / L_DIA, p = i - b * L_DIA;
    float q0 = qmask[p * (B_DIA * 2) + b * 2 + 0];
    float q1 = qmask[p * (B_DIA * 2) + b * 2 + 1];
    int s = (q1 > q0) ? 1 : 0;
    val = l[i * NDIM + t] + spk[s * NDIM + t];
  }
  x[r * NDIM + t] = val;
  xb[r * NDIM + t] = __float2bfloat16(val);
  float ss = val * val;
  #pragma unroll
  for (int off = 32; off > 0; off >>= 1) ss += __shfl_down(ss, off);
  __shared__ float wsum[4];
  int wid = t >> 6, lane = t & 63;
  if (lane == 0) wsum[wid] = ss;
  __syncthreads();
  float inv = rsqrtf(wsum[0] + wsum[1] + wsum[2] + wsum[3]);
  if (t == 0) invn[r] = inv;
  xnb[r * NDIM + t] = __float2bfloat16(val * inv);
}

// ---------------------------------------------------------------------------
// K2: per-(modality,dialogue) 40x40 angular-similarity via MFMA: Xn @ Xn^T
// 3 waves per block; wave w -> row tile [16w,16w+16)
__global__ void k_sim(const __hip_bfloat16* __restrict__ xn, float* __restrict__ sim) {
  int mb = blockIdx.x;          // m*100+b
  int m = mb / B_DIA, b = mb - m * B_DIA;
  int t = threadIdx.x;          // 0..191
  int w = t >> 6, l = t & 63;
  int base = m * N_UTT + b * L_DIA;
  int l15 = l & 15, lk = (l >> 4) * 8;
  int arow = 16 * w + l15; int arowc = (arow < L_DIA) ? arow : (L_DIA - 1);
  f32x4 acc[3] = {{0.f,0.f,0.f,0.f},{0.f,0.f,0.f,0.f},{0.f,0.f,0.f,0.f}};
  const short8* xs = (const short8*)xn;
  for (int k0 = 0; k0 < NDIM; k0 += 32) {
    short8 af = xs[((base + arowc) * NDIM + k0 + lk) >> 3];
    #pragma unroll
    for (int c = 0; c < 3; c++) {
      int bcol = 16 * c + l15; int bcolc = (bcol < L_DIA) ? bcol : (L_DIA - 1);
      short8 bf = xs[((base + bcolc) * NDIM + k0 + lk) >> 3];
      acc[c] = __builtin_amdgcn_mfma_f32_16x16x32_bf16(af, bf, acc[c], 0, 0, 0);
    }
  }
  const float inv_pi = 0.31830988618379067f;
  #pragma unroll
  for (int c = 0; c < 3; c++) {
    #pragma unroll
    for (int rr = 0; rr < 4; rr++) {
      int row = 16 * w + (l >> 4) * 4 + rr;
      int col = 16 * c + l15;
      if (row < L_DIA && col < L_DIA) {
        float cs = fminf(fmaxf(acc[c][rr] * 0.99999f, -1.f), 1.f);
        sim[(mb * L_DIA + row) * L_DIA + col] = 1.0f - acosf(cs) * inv_pi;
      }
    }
  }
}

// ---------------------------------------------------------------------------
// K3: cross-modal diagonal similarities (fp32, exact)
__global__ void k_cross(const float* __restrict__ x, const float* __restrict__ invn,
                        float* __restrict__ cross) {
  int i = blockIdx.x;           // 0..3999
  int t = threadIdx.x;
  float xa = x[(0 * N_UTT + i) * NDIM + t];
  float xv = x[(1 * N_UTT + i) * NDIM + t];
  float xl = x[(2 * N_UTT + i) * NDIM + t];
  float s0 = xa * xv, s1 = xa * xl, s2 = xv * xl;
  #pragma unroll
  for (int off = 32; off > 0; off >>= 1) {
    s0 += __shfl_down(s0, off);
    s1 += __shfl_down(s1, off);
    s2 += __shfl_down(s2, off);
  }
  __shared__ float w0[4], w1[4], w2[4];
  int wid = t >> 6, lane = t & 63;
  if (lane == 0) { w0[wid] = s0; w1[wid] = s1; w2[wid] = s2; }
  __syncthreads();
  if (t == 0) {
    float ina = invn[i], inv = invn[N_UTT + i], inl = invn[2 * N_UTT + i];
    const float inv_pi = 0.31830988618379067f;
    float d0 = fminf(fmaxf((w0[0]+w0[1]+w0[2]+w0[3]) * ina * inv * 0.99999f, -1.f), 1.f);
    float d1 = fminf(fmaxf((w1[0]+w1[1]+w1[2]+w1[3]) * ina * inl * 0.99999f, -1.f), 1.f);
    float d2 = fminf(fmaxf((w2[0]+w2[1]+w2[2]+w2[3]) * inv * inl * 0.99999f, -1.f), 1.f);
    cross[0 * N_UTT + i] = 1.f - acosf(d0) * inv_pi;
    cross[1 * N_UTT + i] = 1.f - acosf(d1) * inv_pi;
    cross[2 * N_UTT + i] = 1.f - acosf(d2) * inv_pi;
  }
}

// ---------------------------------------------------------------------------
// K4: degrees -> dinv
__global__ void k_degree(const float* __restrict__ sim, const float* __restrict__ cross,
                         float* __restrict__ dinv) {
  int r = blockIdx.x * blockDim.x + threadIdx.x;
  if (r >= NNODE) return;
  int m = r / N_UTT, i = r - m * N_UTT;
  int b = i / L_DIA, p = i - b * L_DIA;
  const float* srow = sim + ((m * B_DIA + b) * L_DIA + p) * L_DIA;
  float d = 0.f;
  #pragma unroll 10
  for (int q = 0; q < L_DIA; q++) d += srow[q];
  if (m == 0)      d += cross[i]          + cross[N_UTT + i];
  else if (m == 1) d += cross[i]          + cross[2 * N_UTT + i];
  else             d += cross[N_UTT + i]  + cross[2 * N_UTT + i];
  dinv[r] = rsqrtf(d);
}

// ---------------------------------------------------------------------------
// K5: fold dinv into sim and cross
__global__ void k_norm(float* __restrict__ sim, float* __restrict__ cross,
                       const float* __restrict__ dinv) {
  int e = blockIdx.x * blockDim.x + threadIdx.x;
  const int NSIM = 3 * B_DIA * L_DIA * L_DIA;   // 480000
  if (e < NSIM) {
    int mb = e / (L_DIA * L_DIA), pq = e - mb * (L_DIA * L_DIA);
    int m = mb / B_DIA, b = mb - m * B_DIA;
    int p = pq / L_DIA, q = pq - p * L_DIA;
    int np_ = m * N_UTT + b * L_DIA + p;
    int nq  = m * N_UTT + b * L_DIA + q;
    sim[e] *= dinv[np_] * dinv[nq];
  } else {
    int e2 = e - NSIM;
    if (e2 < 3 * N_UTT) {
      int pair = e2 / N_UTT, i = e2 - pair * N_UTT;
      int m = (pair == 2) ? 1 : 0;
      int n = (pair == 0) ? 1 : 2;
      cross[e2] *= dinv[m * N_UTT + i] * dinv[n * N_UTT + i];
    }
  }
}

// ---------------------------------------------------------------------------
// K6: weight transpose+bf16: Wt[g][n][k] = W_g[k][n]
__global__ void k_wt(const float* __restrict__ W0, const float* __restrict__ Wc,
                     __hip_bfloat16* __restrict__ Wt) {
  int n = blockIdx.x, g = blockIdx.y, k = threadIdx.x;
  const float* src = (g == 0) ? W0 : (Wc + (g - 1) * NDIM * NDIM);
  Wt[(g * NDIM + n) * NDIM + k] = __float2bfloat16(src[k * NDIM + n]);
}

// ---------------------------------------------------------------------------
// MFMA GEMM: C(12000x256) = f(A_bf16(12000x256) @ Wt_bf16^T)
// MODE 0: relu(A@W + bias);  MODE 1: relu(theta*(A@W) + (1-theta)*A)
// 256 thr = 4 waves; wave w: rows [bm+16w, bm+16w+16), all 256 cols
template<int MODE>
__global__ void k_gemm(const __hip_bfloat16* __restrict__ A,
                       const __hip_bfloat16* __restrict__ Wt,
                       const float* __restrict__ bias, float* __restrict__ C,
                       float theta) {
  int bm = blockIdx.x * 64;
  int t = threadIdx.x;
  int w = t >> 6, l = t & 63;
  int l15 = l & 15, lk = (l >> 4) * 8;
  int row = bm + 16 * w + l15;
  int rowc = (row < NNODE) ? row : (NNODE - 1);
  const short8* As = (const short8*)A;
  const short8* Bs = (const short8*)Wt;
  f32x4 acc[16];
  #pragma unroll
  for (int c = 0; c < 16; c++) acc[c] = (f32x4){0.f,0.f,0.f,0.f};
  for (int k0 = 0; k0 < NDIM; k0 += 32) {
    short8 af = As[(rowc * NDIM + k0 + lk) >> 3];
    #pragma unroll
    for (int c = 0; c < 16; c++) {
      short8 bf = Bs[((16 * c + l15) * NDIM + k0 + lk) >> 3];
      acc[c] = __builtin_amdgcn_mfma_f32_16x16x32_bf16(af, bf, acc[c], 0, 0, 0);
    }
  }
  int orow0 = bm + 16 * w + (l >> 4) * 4;
  #pragma unroll
  for (int rr = 0; rr < 4; rr++) {
    int orow = orow0 + rr;
    if (orow >= NNODE) break;
    #pragma unroll
    for (int c = 0; c < 16; c++) {
      int col = 16 * c + l15;
      float vv = acc[c][rr];
      if (MODE == 0) {
        vv += bias[col];
      } else {
        float sup = __bfloat162float(A[orow * NDIM + col]);
        vv = theta * vv + (1.f - theta) * sup;
      }
      C[orow * NDIM + col] = fmaxf(vv, 0.f);
    }
  }
}

// ---------------------------------------------------------------------------
// adj apply + support: sup_bf16 = bf16(0.9*(adjnorm @ h) + 0.1*h0)
// 4-row register tiling: 1 hb read per 4 fma
__global__ void k_adj(const float* __restrict__ h, const float* __restrict__ h0,
                      const float* __restrict__ sim, const float* __restrict__ cross,
                      __hip_bfloat16* __restrict__ sup) {
  int mb = blockIdx.x;          // m*100 + b
  int m = mb / B_DIA, b = mb - m * B_DIA;
  int t = threadIdx.x;
  __shared__ float Sb[L_DIA][L_DIA];
  __shared__ float hb[L_DIA][NDIM];
  const float* simblk = sim + mb * (L_DIA * L_DIA);
  for (int e = t; e < L_DIA * L_DIA; e += 256)
    Sb[e / L_DIA][e % L_DIA] = simblk[e];
  int base = m * N_UTT + b * L_DIA;
  for (int e = t; e < L_DIA * NDIM; e += 256) {
    int r = e >> 8, c = e & 255;
    hb[r][c] = h[(base + r) * NDIM + c];
  }
  __syncthreads();
  for (int p0 = 0; p0 < L_DIA; p0 += 4) {
    float a0 = 0.f, a1 = 0.f, a2 = 0.f, a3 = 0.f;
    for (int q = 0; q < L_DIA; q++) {
      float hv = hb[q][t];
      a0 = fmaf(Sb[p0 + 0][q], hv, a0);
      a1 = fmaf(Sb[p0 + 1][q], hv, a1);
      a2 = fmaf(Sb[p0 + 2][q], hv, a2);
      a3 = fmaf(Sb[p0 + 3][q], hv, a3);
    }
    float accs[4] = {a0, a1, a2, a3};
    #pragma unroll
    for (int pp = 0; pp < 4; pp++) {
      int p = p0 + pp;
      int i = b * L_DIA + p;
      float c0, c1; int o0, o1;
      if (m == 0)      { c0 = cross[i];          o0 = N_UTT + i;     c1 = cross[N_UTT + i];     o1 = 2 * N_UTT + i; }
      else if (m == 1) { c0 = cross[i];          o0 = i;             c1 = cross[2 * N_UTT + i]; o1 = 2 * N_UTT + i; }
      else             { c0 = cross[N_UTT + i];  o0 = i;             c1 = cross[2 * N_UTT + i]; o1 = N_UTT + i; }
      float acc = accs[pp] + c0 * h[o0 * NDIM + t] + c1 * h[o1 * NDIM + t];
      int node = base + p;
      sup[node * NDIM + t] = __float2bfloat16(0.9f * acc + 0.1f * h0[node * NDIM + t]);
    }
  }
}

// ---------------------------------------------------------------------------
// output assembly: out[i] = [a_i, h_a_i, v_i, h_v_i, l_i, h_l_i]
__global__ void k_out(const float* __restrict__ x, const float* __restrict__ h,
                      float* __restrict__ out) {
  int i = blockIdx.x;
  int t = threadIdx.x;
  #pragma unroll
  for (int m = 0; m < 3; m++) {
    out[i * 1536 + m * 512 + t]       = x[(m * N_UTT + i) * NDIM + t];
    out[i * 1536 + m * 512 + 256 + t] = h[(m * N_UTT + i) * NDIM + t];
  }
}

// ---------------------------------------------------------------------------
extern "C" void kernel_launch(void* const* d_in, const int* in_sizes, int n_in,
                              void* d_out, int out_size, void* d_ws, size_t ws_size,
                              hipStream_t stream) {
  const float* a     = (const float*)d_in[0];
  const float* v     = (const float*)d_in[1];
  const float* l     = (const float*)d_in[2];
  const float* qmask = (const float*)d_in[3];
  const float* spk   = (const float*)d_in[4];
  const float* W0    = (const float*)d_in[5];
  const float* b0    = (const float*)d_in[6];
  const float* Wc    = (const float*)d_in[7];
  float* out = (float*)d_out;
  float* ws  = (float*)d_ws;

  float* x  = ws;                         // 3,072,000 fl
  float* h0 = ws +  3072000;              // 3,072,000
  float* hA = ws +  6144000;              // 3,072,000 (aliases xn_bf16)
  float* hB = ws +  9216000;              // 3,072,000 (aliases x_bf16)
  __hip_bfloat16* xnb  = (__hip_bfloat16*)hA;
  __hip_bfloat16* xb   = (__hip_bfloat16*)hB;
  __hip_bfloat16* supb = (__hip_bfloat16*)(ws + 12288000); // 1,536,000 fl
  __hip_bfloat16* Wt   = (__hip_bfloat16*)(ws + 13824000); // 163,840 fl
  float* sim   = ws + 13987840;           // 480,000
  float* cross = ws + 14467840;           // 12,000
  float* invn  = ws + 14479840;           // 12,000
  float* dinv  = ws + 14491840;           // 12,000
  // total: 14,503,840 fl = 58.0 MB

  k_wt<<<dim3(NDIM, 5), NDIM, 0, stream>>>(W0, Wc, Wt);
  k_build_x<<<NNODE, 256, 0, stream>>>(a, v, l, qmask, spk, x, invn, xb, xnb);
  k_sim<<<3 * B_DIA, 192, 0, stream>>>(xnb, sim);
  k_cross<<<N_UTT, 256, 0, stream>>>(x, invn, cross);
  k_degree<<<(NNODE + 255) / 256, 256, 0, stream>>>(sim, cross, dinv);
  k_norm<<<(3 * B_DIA * L_DIA * L_DIA + 3 * N_UTT + 255) / 256, 256, 0, stream>>>(sim, cross, dinv);

  k_gemm<0><<<(NNODE + 63) / 64, 256, 0, stream>>>(xb, Wt, b0, h0, 0.f);

  const float thetas[NLAYERS] = {0.40546510810816438f, 0.22314355131420976f,
                                 0.15415067982725836f, 0.11778303565638346f};
  const float* hcur = h0;
  float* houts[NLAYERS] = {hA, hB, hA, hB};
  for (int i = 0; i < NLAYERS; i++) {
    k_adj<<<3 * B_DIA, 256, 0, stream>>>(hcur, h0, sim, cross, supb);
    k_gemm<1><<<(NNODE + 63) / 64, 256, 0, stream>>>(
        supb, Wt + (i + 1) * NDIM * NDIM, nullptr, houts[i], thetas[i]);
    hcur = houts[i];
  }
  k_out<<<N_UTT, 256, 0, stream>>>(x, hcur, out);
}

// Round 3
// 218.827 us; speedup vs baseline: 2.9180x; 2.9180x over previous
//
#include <hip/hip_runtime.h>
#include <hip/hip_bf16.h>

#define N_UTT 4000
#define NDIM 256
#define B_DIA 100
#define L_DIA 40
#define NNODE 12000   // 3*N_UTT
#define NLAYERS 4

typedef __attribute__((ext_vector_type(8))) short short8;   // 8 bf16 (4 VGPRs)
typedef __attribute__((ext_vector_type(4))) float f32x4;    // MFMA acc

// ---------------------------------------------------------------------------
// K1: build x = concat(a, v, l + spk_emb[argmax(q)]), invn, x_bf16, xn_bf16
__global__ void k_build_x(const float* __restrict__ a, const float* __restrict__ v,
                          const float* __restrict__ l, const float* __restrict__ qmask,
                          const float* __restrict__ spk, float* __restrict__ x,
                          float* __restrict__ invn,
                          __hip_bfloat16* __restrict__ xb,
                          __hip_bfloat16* __restrict__ xnb) {
  int r = blockIdx.x;          // 0..11999
  int t = threadIdx.x;         // 0..255
  int m = r / N_UTT;
  int i = r - m * N_UTT;
  float val;
  if (m == 0) val = a[i * NDIM + t];
  else if (m == 1) val = v[i * NDIM + t];
  else {
    int b = i / L_DIA, p = i - b * L_DIA;
    float q0 = qmask[p * (B_DIA * 2) + b * 2 + 0];
    float q1 = qmask[p * (B_DIA * 2) + b * 2 + 1];
    int s = (q1 > q0) ? 1 : 0;
    val = l[i * NDIM + t] + spk[s * NDIM + t];
  }
  x[r * NDIM + t] = val;
  xb[r * NDIM + t] = __float2bfloat16(val);
  float ss = val * val;
  #pragma unroll
  for (int off = 32; off > 0; off >>= 1) ss += __shfl_down(ss, off);
  __shared__ float wsum[4];
  int wid = t >> 6, lane = t & 63;
  if (lane == 0) wsum[wid] = ss;
  __syncthreads();
  float inv = rsqrtf(wsum[0] + wsum[1] + wsum[2] + wsum[3]);
  if (t == 0) invn[r] = inv;
  xnb[r * NDIM + t] = __float2bfloat16(val * inv);
}

// ---------------------------------------------------------------------------
// K2: per-(modality,dialogue) 40x40 angular-similarity via MFMA: Xn @ Xn^T
__global__ void k_sim(const __hip_bfloat16* __restrict__ xn, float* __restrict__ sim) {
  int mb = blockIdx.x;          // m*100+b
  int m = mb / B_DIA, b = mb - m * B_DIA;
  int t = threadIdx.x;          // 0..191
  int w = t >> 6, l = t & 63;
  int base = m * N_UTT + b * L_DIA;
  int l15 = l & 15, lk = (l >> 4) * 8;
  int arow = 16 * w + l15; int arowc = (arow < L_DIA) ? arow : (L_DIA - 1);
  f32x4 acc[3] = {{0.f,0.f,0.f,0.f},{0.f,0.f,0.f,0.f},{0.f,0.f,0.f,0.f}};
  const short8* xs = (const short8*)xn;
  for (int k0 = 0; k0 < NDIM; k0 += 32) {
    short8 af = xs[((base + arowc) * NDIM + k0 + lk) >> 3];
    #pragma unroll
    for (int c = 0; c < 3; c++) {
      int bcol = 16 * c + l15; int bcolc = (bcol < L_DIA) ? bcol : (L_DIA - 1);
      short8 bf = xs[((base + bcolc) * NDIM + k0 + lk) >> 3];
      acc[c] = __builtin_amdgcn_mfma_f32_16x16x32_bf16(af, bf, acc[c], 0, 0, 0);
    }
  }
  const float inv_pi = 0.31830988618379067f;
  #pragma unroll
  for (int c = 0; c < 3; c++) {
    #pragma unroll
    for (int rr = 0; rr < 4; rr++) {
      int row = 16 * w + (l >> 4) * 4 + rr;
      int col = 16 * c + l15;
      if (row < L_DIA && col < L_DIA) {
        float cs = fminf(fmaxf(acc[c][rr] * 0.99999f, -1.f), 1.f);
        sim[(mb * L_DIA + row) * L_DIA + col] = 1.0f - acosf(cs) * inv_pi;
      }
    }
  }
}

// ---------------------------------------------------------------------------
// K3: cross-modal diagonal similarities (fp32, exact)
__global__ void k_cross(const float* __restrict__ x, const float* __restrict__ invn,
                        float* __restrict__ cross) {
  int i = blockIdx.x;           // 0..3999
  int t = threadIdx.x;
  float xa = x[(0 * N_UTT + i) * NDIM + t];
  float xv = x[(1 * N_UTT + i) * NDIM + t];
  float xl = x[(2 * N_UTT + i) * NDIM + t];
  float s0 = xa * xv, s1 = xa * xl, s2 = xv * xl;
  #pragma unroll
  for (int off = 32; off > 0; off >>= 1) {
    s0 += __shfl_down(s0, off);
    s1 += __shfl_down(s1, off);
    s2 += __shfl_down(s2, off);
  }
  __shared__ float w0[4], w1[4], w2[4];
  int wid = t >> 6, lane = t & 63;
  if (lane == 0) { w0[wid] = s0; w1[wid] = s1; w2[wid] = s2; }
  __syncthreads();
  if (t == 0) {
    float ina = invn[i], inv = invn[N_UTT + i], inl = invn[2 * N_UTT + i];
    const float inv_pi = 0.31830988618379067f;
    float d0 = fminf(fmaxf((w0[0]+w0[1]+w0[2]+w0[3]) * ina * inv * 0.99999f, -1.f), 1.f);
    float d1 = fminf(fmaxf((w1[0]+w1[1]+w1[2]+w1[3]) * ina * inl * 0.99999f, -1.f), 1.f);
    float d2 = fminf(fmaxf((w2[0]+w2[1]+w2[2]+w2[3]) * inv * inl * 0.99999f, -1.f), 1.f);
    cross[0 * N_UTT + i] = 1.f - acosf(d0) * inv_pi;
    cross[1 * N_UTT + i] = 1.f - acosf(d1) * inv_pi;
    cross[2 * N_UTT + i] = 1.f - acosf(d2) * inv_pi;
  }
}

// ---------------------------------------------------------------------------
// K4: degrees -> dinv (reads raw sim/cross)
__global__ void k_degree(const float* __restrict__ sim, const float* __restrict__ cross,
                         float* __restrict__ dinv) {
  int r = blockIdx.x * blockDim.x + threadIdx.x;
  if (r >= NNODE) return;
  int m = r / N_UTT, i = r - m * N_UTT;
  int b = i / L_DIA, p = i - b * L_DIA;
  const float* srow = sim + ((m * B_DIA + b) * L_DIA + p) * L_DIA;
  float d = 0.f;
  #pragma unroll 10
  for (int q = 0; q < L_DIA; q++) d += srow[q];
  if (m == 0)      d += cross[i]          + cross[N_UTT + i];
  else if (m == 1) d += cross[i]          + cross[2 * N_UTT + i];
  else             d += cross[N_UTT + i]  + cross[2 * N_UTT + i];
  dinv[r] = rsqrtf(d);
}

// ---------------------------------------------------------------------------
// K5: fold dinv AND the (1-ALPHA)=0.9 propagation factor into sim and cross
__global__ void k_norm(float* __restrict__ sim, float* __restrict__ cross,
                       const float* __restrict__ dinv) {
  int e = blockIdx.x * blockDim.x + threadIdx.x;
  const int NSIM = 3 * B_DIA * L_DIA * L_DIA;   // 480000
  if (e < NSIM) {
    int mb = e / (L_DIA * L_DIA), pq = e - mb * (L_DIA * L_DIA);
    int m = mb / B_DIA, b = mb - m * B_DIA;
    int p = pq / L_DIA, q = pq - p * L_DIA;
    int np_ = m * N_UTT + b * L_DIA + p;
    int nq  = m * N_UTT + b * L_DIA + q;
    sim[e] *= 0.9f * dinv[np_] * dinv[nq];
  } else {
    int e2 = e - NSIM;
    if (e2 < 3 * N_UTT) {
      int pair = e2 / N_UTT, i = e2 - pair * N_UTT;
      int m = (pair == 2) ? 1 : 0;
      int n = (pair == 0) ? 1 : 2;
      cross[e2] *= 0.9f * dinv[m * N_UTT + i] * dinv[n * N_UTT + i];
    }
  }
}

// ---------------------------------------------------------------------------
// K6: weight transpose+bf16: Wt[g][n][k] = W_g[k][n]
__global__ void k_wt(const float* __restrict__ W0, const float* __restrict__ Wc,
                     __hip_bfloat16* __restrict__ Wt) {
  int n = blockIdx.x, g = blockIdx.y, k = threadIdx.x;
  const float* src = (g == 0) ? W0 : (Wc + (g - 1) * NDIM * NDIM);
  Wt[(g * NDIM + n) * NDIM + k] = __float2bfloat16(src[k * NDIM + n]);
}

// ---------------------------------------------------------------------------
// MFMA GEMM: one wave per block; wave: 16 rows x 128 cols, K=256
// MODE 0: relu(A@W + bias);  MODE 1: relu(theta*(A@W) + (1-theta)*A)
template<int MODE>
__global__ void k_gemm(const __hip_bfloat16* __restrict__ A,
                       const __hip_bfloat16* __restrict__ Wt,
                       const float* __restrict__ bias, float* __restrict__ C,
                       float theta) {
  int rt = blockIdx.x >> 1;       // row tile 0..749
  int ch = blockIdx.x & 1;        // col half 0..1
  int l = threadIdx.x;            // 0..63
  int l15 = l & 15, lk = (l >> 4) * 8;
  int row = rt * 16 + l15;        // 750*16 == 12000, always in range
  const short8* As = (const short8*)A;
  const short8* Bs = (const short8*)Wt;
  f32x4 acc[8];
  #pragma unroll
  for (int c = 0; c < 8; c++) acc[c] = (f32x4){0.f,0.f,0.f,0.f};
  for (int k0 = 0; k0 < NDIM; k0 += 32) {
    short8 af = As[(row * NDIM + k0 + lk) >> 3];
    #pragma unroll
    for (int c = 0; c < 8; c++) {
      int col = ch * 128 + c * 16 + l15;
      short8 bf = Bs[(col * NDIM + k0 + lk) >> 3];
      acc[c] = __builtin_amdgcn_mfma_f32_16x16x32_bf16(af, bf, acc[c], 0, 0, 0);
    }
  }
  int orow0 = rt * 16 + (l >> 4) * 4;
  #pragma unroll
  for (int rr = 0; rr < 4; rr++) {
    int orow = orow0 + rr;
    #pragma unroll
    for (int c = 0; c < 8; c++) {
      int col = ch * 128 + c * 16 + l15;
      float vv = acc[c][rr];
      if (MODE == 0) {
        vv += bias[col];
      } else {
        float sup = __bfloat162float(A[orow * NDIM + col]);
        vv = theta * vv + (1.f - theta) * sup;
      }
      C[orow * NDIM + col] = fmaxf(vv, 0.f);
    }
  }
}

// ---------------------------------------------------------------------------
// adj apply + support: sup_bf16 = bf16((S'@h + cross' terms) + 0.1*h0)
// (0.9 pre-folded into S'/cross'). Grid 3000: block = 4 rows of one (m,b);
// thread t: row (t>>6), cols 4*(t&63)..+4. No LDS h staging (L1/L2-hot).
__global__ void k_adj(const float* __restrict__ h, const float* __restrict__ h0,
                      const float* __restrict__ sim, const float* __restrict__ cross,
                      __hip_bfloat16* __restrict__ sup) {
  int bid = blockIdx.x;
  int mb = bid / 10, p4 = bid - mb * 10;   // 10 row-groups per (m,b)
  int m = mb / B_DIA, b = mb - m * B_DIA;
  int t = threadIdx.x;
  int r = t >> 6;                  // 0..3
  int c4 = (t & 63) * 4;           // column base
  int p = p4 * 4 + r;
  int base = m * N_UTT + b * L_DIA;
  int node = base + p;
  int i = b * L_DIA + p;

  __shared__ float Sb[4][L_DIA];
  if (t < 4 * L_DIA) {
    int rr = t / L_DIA, qq = t - rr * L_DIA;
    Sb[rr][qq] = sim[(mb * L_DIA + p4 * 4 + rr) * L_DIA + qq];
  }
  __syncthreads();

  const float4* h4 = (const float4*)h;
  float4 acc = {0.f, 0.f, 0.f, 0.f};
  #pragma unroll 8
  for (int q = 0; q < L_DIA; q++) {
    float s = Sb[r][q];
    float4 hv = h4[((base + q) * NDIM + c4) >> 2];
    acc.x = fmaf(s, hv.x, acc.x);
    acc.y = fmaf(s, hv.y, acc.y);
    acc.z = fmaf(s, hv.z, acc.z);
    acc.w = fmaf(s, hv.w, acc.w);
  }
  float c0, c1; int o0, o1;
  if (m == 0)      { c0 = cross[i];          o0 = N_UTT + i;     c1 = cross[N_UTT + i];     o1 = 2 * N_UTT + i; }
  else if (m == 1) { c0 = cross[i];          o0 = i;             c1 = cross[2 * N_UTT + i]; o1 = 2 * N_UTT + i; }
  else             { c0 = cross[N_UTT + i];  o0 = i;             c1 = cross[2 * N_UTT + i]; o1 = N_UTT + i; }
  float4 hv0 = h4[(o0 * NDIM + c4) >> 2];
  float4 hv1 = h4[(o1 * NDIM + c4) >> 2];
  float4 h0v = ((const float4*)h0)[(node * NDIM + c4) >> 2];
  float v0 = acc.x + c0 * hv0.x + c1 * hv1.x + 0.1f * h0v.x;
  float v1 = acc.y + c0 * hv0.y + c1 * hv1.y + 0.1f * h0v.y;
  float v2 = acc.z + c0 * hv0.z + c1 * hv1.z + 0.1f * h0v.z;
  float v3 = acc.w + c0 * hv0.w + c1 * hv1.w + 0.1f * h0v.w;
  union { __hip_bfloat16 bh[4]; uint2 u; } pk;
  pk.bh[0] = __float2bfloat16(v0);
  pk.bh[1] = __float2bfloat16(v1);
  pk.bh[2] = __float2bfloat16(v2);
  pk.bh[3] = __float2bfloat16(v3);
  *(uint2*)&sup[node * NDIM + c4] = pk.u;
}

// ---------------------------------------------------------------------------
// output assembly (float4): out[i] = [a_i, h_a_i, v_i, h_v_i, l_i, h_l_i]
__global__ void k_out(const float* __restrict__ x, const float* __restrict__ h,
                      float* __restrict__ out) {
  int i = blockIdx.x;
  int t = threadIdx.x;             // 0..127
  const float4* x4 = (const float4*)x;
  const float4* h4 = (const float4*)h;
  float4* o4 = (float4*)out;
  #pragma unroll
  for (int it = 0; it < 3; it++) {
    int f = t + 128 * it;          // 0..383
    int m = f >> 7, rem = f & 127;
    const float4* src = (rem < 64) ? x4 : h4;
    o4[i * 384 + f] = src[(m * N_UTT + i) * 64 + (rem & 63)];
  }
}

// ---------------------------------------------------------------------------
extern "C" void kernel_launch(void* const* d_in, const int* in_sizes, int n_in,
                              void* d_out, int out_size, void* d_ws, size_t ws_size,
                              hipStream_t stream) {
  const float* a     = (const float*)d_in[0];
  const float* v     = (const float*)d_in[1];
  const float* l     = (const float*)d_in[2];
  const float* qmask = (const float*)d_in[3];
  const float* spk   = (const float*)d_in[4];
  const float* W0    = (const float*)d_in[5];
  const float* b0    = (const float*)d_in[6];
  const float* Wc    = (const float*)d_in[7];
  float* out = (float*)d_out;
  float* ws  = (float*)d_ws;

  float* x  = ws;                         // 3,072,000 fl
  float* h0 = ws +  3072000;              // 3,072,000
  float* hA = ws +  6144000;              // 3,072,000 (aliases xn_bf16)
  float* hB = ws +  9216000;              // 3,072,000 (aliases x_bf16)
  __hip_bfloat16* xnb  = (__hip_bfloat16*)hA;
  __hip_bfloat16* xb   = (__hip_bfloat16*)hB;
  __hip_bfloat16* supb = (__hip_bfloat16*)(ws + 12288000); // 1,536,000 fl
  __hip_bfloat16* Wt   = (__hip_bfloat16*)(ws + 13824000); // 163,840 fl
  float* sim   = ws + 13987840;           // 480,000
  float* cross = ws + 14467840;           // 12,000
  float* invn  = ws + 14479840;           // 12,000
  float* dinv  = ws + 14491840;           // 12,000
  // total: 14,503,840 fl = 58.0 MB

  k_wt<<<dim3(NDIM, 5), NDIM, 0, stream>>>(W0, Wc, Wt);
  k_build_x<<<NNODE, 256, 0, stream>>>(a, v, l, qmask, spk, x, invn, xb, xnb);
  k_sim<<<3 * B_DIA, 192, 0, stream>>>(xnb, sim);
  k_cross<<<N_UTT, 256, 0, stream>>>(x, invn, cross);
  k_degree<<<(NNODE + 255) / 256, 256, 0, stream>>>(sim, cross, dinv);
  k_norm<<<(3 * B_DIA * L_DIA * L_DIA + 3 * N_UTT + 255) / 256, 256, 0, stream>>>(sim, cross, dinv);

  k_gemm<0><<<2 * (NNODE / 16), 64, 0, stream>>>(xb, Wt, b0, h0, 0.f);

  const float thetas[NLAYERS] = {0.40546510810816438f, 0.22314355131420976f,
                                 0.15415067982725836f, 0.11778303565638346f};
  const float* hcur = h0;
  float* houts[NLAYERS] = {hA, hB, hA, hB};
  for (int i = 0; i < NLAYERS; i++) {
    k_adj<<<3 * B_DIA * 10, 256, 0, stream>>>(hcur, h0, sim, cross, supb);
    k_gemm<1><<<2 * (NNODE / 16), 64, 0, stream>>>(
        supb, Wt + (i + 1) * NDIM * NDIM, nullptr, houts[i], thetas[i]);
    hcur = houts[i];
  }
  k_out<<<N_UTT, 128, 0, stream>>>(x, hcur, out);
}

// Round 4
// 200.410 us; speedup vs baseline: 3.1862x; 1.0919x over previous
//
#include <hip/hip_runtime.h>
#include <hip/hip_bf16.h>

#define N_UTT 4000
#define NDIM 256
#define B_DIA 100
#define L_DIA 40
#define NNODE 12000   // 3*N_UTT
#define NLAYERS 4

typedef __attribute__((ext_vector_type(8))) short short8;   // 8 bf16 (4 VGPRs)
typedef __attribute__((ext_vector_type(4))) float f32x4;    // MFMA acc

// ---------------------------------------------------------------------------
// K1: build x = concat(a, v, l + spk_emb[argmax(q)]); write x-part of out,
// x_bf16, xn_bf16. One block per node row.
__global__ void k_build_x(const float* __restrict__ a, const float* __restrict__ v,
                          const float* __restrict__ l, const float* __restrict__ qmask,
                          const float* __restrict__ spk, float* __restrict__ out,
                          __hip_bfloat16* __restrict__ xb,
                          __hip_bfloat16* __restrict__ xnb) {
  int r = blockIdx.x;          // 0..11999
  int t = threadIdx.x;         // 0..255
  int m = r / N_UTT;
  int i = r - m * N_UTT;
  float val;
  if (m == 0) val = a[i * NDIM + t];
  else if (m == 1) val = v[i * NDIM + t];
  else {
    int b = i / L_DIA, p = i - b * L_DIA;
    float q0 = qmask[p * (B_DIA * 2) + b * 2 + 0];
    float q1 = qmask[p * (B_DIA * 2) + b * 2 + 1];
    int s = (q1 > q0) ? 1 : 0;
    val = l[i * NDIM + t] + spk[s * NDIM + t];
  }
  out[i * 1536 + m * 512 + t] = val;           // x-part of final output
  xb[r * NDIM + t] = __float2bfloat16(val);
  float ss = val * val;
  #pragma unroll
  for (int off = 32; off > 0; off >>= 1) ss += __shfl_down(ss, off);
  __shared__ float wsum[4];
  int wid = t >> 6, lane = t & 63;
  if (lane == 0) wsum[wid] = ss;
  __syncthreads();
  float inv = rsqrtf(wsum[0] + wsum[1] + wsum[2] + wsum[3]);
  xnb[r * NDIM + t] = __float2bfloat16(val * inv);
}

// ---------------------------------------------------------------------------
// K2 (fused sim+cross+degree+norm): one block per dialogue, 192 thr = 3 waves.
// Wave w: modality w sim block (3x3 16-tiles) + cross-diag with partner
// modality (w+1)%3. Then LDS row-sums -> dinv -> normalized writes.
__global__ void k_graph(const __hip_bfloat16* __restrict__ xn,
                        float* __restrict__ sim, float* __restrict__ cross) {
  int b = blockIdx.x;           // dialogue
  int t = threadIdx.x;          // 0..191
  int w = t >> 6, l = t & 63;
  int l15 = l & 15, lk = (l >> 4) * 8;
  int m = w;
  int pm = (w + 1) % 3;
  int pairidx = (w == 0) ? 0 : (w == 1) ? 2 : 1;  // (0,1)->0 (1,2)->2 (2,0)->1
  int obase = m * N_UTT + b * L_DIA;
  int pbase = pm * N_UTT + b * L_DIA;
  const short8* xs = (const short8*)xn;

  int rowi[3];
  #pragma unroll
  for (int rt = 0; rt < 3; rt++) {
    int rr_ = 16 * rt + l15;
    rowi[rt] = (rr_ < L_DIA) ? rr_ : (L_DIA - 1);
  }
  f32x4 s[3][3], cacc[3];
  #pragma unroll
  for (int rt = 0; rt < 3; rt++) {
    cacc[rt] = (f32x4){0.f,0.f,0.f,0.f};
    #pragma unroll
    for (int ct = 0; ct < 3; ct++) s[rt][ct] = (f32x4){0.f,0.f,0.f,0.f};
  }
  for (int k0 = 0; k0 < NDIM; k0 += 32) {
    short8 own[3], par[3];
    #pragma unroll
    for (int rt = 0; rt < 3; rt++) own[rt] = xs[((obase + rowi[rt]) * NDIM + k0 + lk) >> 3];
    #pragma unroll
    for (int rt = 0; rt < 3; rt++) par[rt] = xs[((pbase + rowi[rt]) * NDIM + k0 + lk) >> 3];
    #pragma unroll
    for (int rt = 0; rt < 3; rt++) {
      #pragma unroll
      for (int ct = 0; ct < 3; ct++)
        s[rt][ct] = __builtin_amdgcn_mfma_f32_16x16x32_bf16(own[rt], own[ct], s[rt][ct], 0, 0, 0);
      cacc[rt] = __builtin_amdgcn_mfma_f32_16x16x32_bf16(own[rt], par[rt], cacc[rt], 0, 0, 0);
    }
  }
  __shared__ float sim_s[3][L_DIA][41];
  __shared__ float cr_s[3][L_DIA];
  __shared__ float dinv_s[3][L_DIA];
  const float inv_pi = 0.31830988618379067f;
  #pragma unroll
  for (int rt = 0; rt < 3; rt++) {
    #pragma unroll
    for (int ct = 0; ct < 3; ct++) {
      #pragma unroll
      for (int rr = 0; rr < 4; rr++) {
        int row = 16 * rt + (l >> 4) * 4 + rr;
        int col = 16 * ct + l15;
        if (row < L_DIA && col < L_DIA) {
          float cs = fminf(fmaxf(s[rt][ct][rr] * 0.99999f, -1.f), 1.f);
          sim_s[m][row][col] = 1.0f - acosf(cs) * inv_pi;
        }
      }
    }
    #pragma unroll
    for (int rr = 0; rr < 4; rr++) {
      if (l15 == ((l >> 4) * 4 + rr)) {
        int dgi = 16 * rt + l15;
        if (dgi < L_DIA) {
          float cs = fminf(fmaxf(cacc[rt][rr] * 0.99999f, -1.f), 1.f);
          cr_s[pairidx][dgi] = 1.0f - acosf(cs) * inv_pi;
        }
      }
    }
  }
  __syncthreads();
  if (t < 3 * L_DIA) {
    int mm = t / L_DIA, p = t - mm * L_DIA;
    float d = 0.f;
    #pragma unroll 10
    for (int q = 0; q < L_DIA; q++) d += sim_s[mm][p][q];
    if (mm == 0)      d += cr_s[0][p] + cr_s[1][p];
    else if (mm == 1) d += cr_s[0][p] + cr_s[2][p];
    else              d += cr_s[1][p] + cr_s[2][p];
    dinv_s[mm][p] = rsqrtf(d);
  }
  __syncthreads();
  // normalized sim (0.9 = 1-ALPHA folded)
  for (int e = l; e < L_DIA * L_DIA; e += 64) {
    int row = e / L_DIA, col = e - row * L_DIA;
    sim[((m * B_DIA + b) * L_DIA + row) * L_DIA + col] =
        0.9f * sim_s[m][row][col] * dinv_s[m][row] * dinv_s[m][col];
  }
  if (t < 3 * L_DIA) {
    int pr = t / L_DIA, ii = t - pr * L_DIA;
    int ma = (pr == 2) ? 1 : 0;
    int na = (pr == 0) ? 1 : 2;
    cross[pr * N_UTT + b * L_DIA + ii] =
        0.9f * cr_s[pr][ii] * dinv_s[ma][ii] * dinv_s[na][ii];
  }
}

// ---------------------------------------------------------------------------
// K3: weight transpose+bf16 via LDS tile: Wt[g][n][k] = W_g[k][n]
// grid (4,4,5), 256 thr: 64x64 tile per block
__global__ void k_wt(const float* __restrict__ W0, const float* __restrict__ Wc,
                     __hip_bfloat16* __restrict__ Wt) {
  int k0 = blockIdx.x * 64, n0 = blockIdx.y * 64, g = blockIdx.z;
  int t = threadIdx.x;
  const float* src = (g == 0) ? W0 : (Wc + (g - 1) * NDIM * NDIM);
  __shared__ float tile[64][65];
  #pragma unroll
  for (int it = 0; it < 16; it++) {
    int e = t + 256 * it;
    int row = e >> 6, col = e & 63;
    tile[row][col] = src[(k0 + row) * NDIM + n0 + col];
  }
  __syncthreads();
  #pragma unroll
  for (int it = 0; it < 16; it++) {
    int e = t + 256 * it;
    int row = e >> 6, col = e & 63;
    Wt[(g * NDIM + n0 + row) * NDIM + k0 + col] = __float2bfloat16(tile[col][row]);
  }
}

// ---------------------------------------------------------------------------
// MFMA GEMM: one wave per block, 16 rows x 64 cols, K=256.
// MODE 0: relu(A@W + bias) -> C[12000x256]
// MODE 1: relu(theta*(A@W) + (1-theta)*A) -> C[12000x256]
// MODE 2: like MODE 1 but scatter into out h-slots
template<int MODE>
__global__ void k_gemm(const __hip_bfloat16* __restrict__ A,
                       const __hip_bfloat16* __restrict__ Wt,
                       const float* __restrict__ bias, float* __restrict__ C,
                       float theta) {
  int rt = blockIdx.x >> 2;       // row tile 0..749
  int ch = blockIdx.x & 3;        // col quarter
  int l = threadIdx.x;            // 0..63
  int l15 = l & 15, lk = (l >> 4) * 8;
  int row = rt * 16 + l15;
  const short8* As = (const short8*)A;
  const short8* Bs = (const short8*)Wt;
  f32x4 acc[4];
  #pragma unroll
  for (int c = 0; c < 4; c++) acc[c] = (f32x4){0.f,0.f,0.f,0.f};
  for (int k0 = 0; k0 < NDIM; k0 += 32) {
    short8 af = As[(row * NDIM + k0 + lk) >> 3];
    #pragma unroll
    for (int c = 0; c < 4; c++) {
      int col = ch * 64 + c * 16 + l15;
      short8 bf = Bs[(col * NDIM + k0 + lk) >> 3];
      acc[c] = __builtin_amdgcn_mfma_f32_16x16x32_bf16(af, bf, acc[c], 0, 0, 0);
    }
  }
  int orow0 = rt * 16 + (l >> 4) * 4;
  #pragma unroll
  for (int rr = 0; rr < 4; rr++) {
    int orow = orow0 + rr;
    #pragma unroll
    for (int c = 0; c < 4; c++) {
      int col = ch * 64 + c * 16 + l15;
      float vv = acc[c][rr];
      if (MODE == 0) {
        vv += bias[col];
      } else {
        float sup = __bfloat162float(A[orow * NDIM + col]);
        vv = theta * vv + (1.f - theta) * sup;
      }
      vv = fmaxf(vv, 0.f);
      if (MODE == 2) {
        int mm = orow / N_UTT;
        int ii = orow - mm * N_UTT;
        C[ii * 1536 + mm * 512 + 256 + col] = vv;
      } else {
        C[orow * NDIM + col] = vv;
      }
    }
  }
}

// ---------------------------------------------------------------------------
// adj apply + support: sup_bf16 = bf16((S'@h + cross' terms) + 0.1*h0)
// (0.9 pre-folded). Grid 3000: block = 4 rows of one (m,b).
__global__ void k_adj(const float* __restrict__ h, const float* __restrict__ h0,
                      const float* __restrict__ sim, const float* __restrict__ cross,
                      __hip_bfloat16* __restrict__ sup) {
  int bid = blockIdx.x;
  int mb = bid / 10, p4 = bid - mb * 10;
  int m = mb / B_DIA, b = mb - m * B_DIA;
  int t = threadIdx.x;
  int r = t >> 6;                  // 0..3
  int c4 = (t & 63) * 4;
  int p = p4 * 4 + r;
  int base = m * N_UTT + b * L_DIA;
  int node = base + p;
  int i = b * L_DIA + p;

  __shared__ float Sb[4][L_DIA];
  if (t < 4 * L_DIA) {
    int rr = t / L_DIA, qq = t - rr * L_DIA;
    Sb[rr][qq] = sim[(mb * L_DIA + p4 * 4 + rr) * L_DIA + qq];
  }
  __syncthreads();

  const float4* h4 = (const float4*)h;
  float4 acc = {0.f, 0.f, 0.f, 0.f};
  #pragma unroll 8
  for (int q = 0; q < L_DIA; q++) {
    float s = Sb[r][q];
    float4 hv = h4[((base + q) * NDIM + c4) >> 2];
    acc.x = fmaf(s, hv.x, acc.x);
    acc.y = fmaf(s, hv.y, acc.y);
    acc.z = fmaf(s, hv.z, acc.z);
    acc.w = fmaf(s, hv.w, acc.w);
  }
  float c0, c1; int o0, o1;
  if (m == 0)      { c0 = cross[i];          o0 = N_UTT + i;     c1 = cross[N_UTT + i];     o1 = 2 * N_UTT + i; }
  else if (m == 1) { c0 = cross[i];          o0 = i;             c1 = cross[2 * N_UTT + i]; o1 = 2 * N_UTT + i; }
  else             { c0 = cross[N_UTT + i];  o0 = i;             c1 = cross[2 * N_UTT + i]; o1 = N_UTT + i; }
  float4 hv0 = h4[(o0 * NDIM + c4) >> 2];
  float4 hv1 = h4[(o1 * NDIM + c4) >> 2];
  float4 h0v = ((const float4*)h0)[(node * NDIM + c4) >> 2];
  float v0 = acc.x + c0 * hv0.x + c1 * hv1.x + 0.1f * h0v.x;
  float v1 = acc.y + c0 * hv0.y + c1 * hv1.y + 0.1f * h0v.y;
  float v2 = acc.z + c0 * hv0.z + c1 * hv1.z + 0.1f * h0v.z;
  float v3 = acc.w + c0 * hv0.w + c1 * hv1.w + 0.1f * h0v.w;
  union { __hip_bfloat16 bh[4]; uint2 u; } pk;
  pk.bh[0] = __float2bfloat16(v0);
  pk.bh[1] = __float2bfloat16(v1);
  pk.bh[2] = __float2bfloat16(v2);
  pk.bh[3] = __float2bfloat16(v3);
  *(uint2*)&sup[node * NDIM + c4] = pk.u;
}

// ---------------------------------------------------------------------------
extern "C" void kernel_launch(void* const* d_in, const int* in_sizes, int n_in,
                              void* d_out, int out_size, void* d_ws, size_t ws_size,
                              hipStream_t stream) {
  const float* a     = (const float*)d_in[0];
  const float* v     = (const float*)d_in[1];
  const float* l     = (const float*)d_in[2];
  const float* qmask = (const float*)d_in[3];
  const float* spk   = (const float*)d_in[4];
  const float* W0    = (const float*)d_in[5];
  const float* b0    = (const float*)d_in[6];
  const float* Wc    = (const float*)d_in[7];
  float* out = (float*)d_out;
  float* ws  = (float*)d_ws;

  float* h0 = ws;                         // 3,072,000 fl
  float* hA = ws + 3072000;               // 3,072,000 (aliases xnb)
  float* hB = ws + 6144000;               // 3,072,000 (aliases xb)
  __hip_bfloat16* xnb  = (__hip_bfloat16*)hA;
  __hip_bfloat16* xb   = (__hip_bfloat16*)hB;
  __hip_bfloat16* supb = (__hip_bfloat16*)(ws + 9216000);   // 1,536,000 fl
  __hip_bfloat16* Wt   = (__hip_bfloat16*)(ws + 10752000);  // 163,840 fl
  float* sim   = ws + 10915840;           // 480,000
  float* cross = ws + 11395840;           // 12,000
  // total: 11,407,840 fl = 45.6 MB

  k_wt<<<dim3(4, 4, 5), 256, 0, stream>>>(W0, Wc, Wt);
  k_build_x<<<NNODE, 256, 0, stream>>>(a, v, l, qmask, spk, out, xb, xnb);
  k_graph<<<B_DIA, 192, 0, stream>>>(xnb, sim, cross);

  k_gemm<0><<<4 * (NNODE / 16), 64, 0, stream>>>(xb, Wt, b0, h0, 0.f);

  const float thetas[NLAYERS] = {0.40546510810816438f, 0.22314355131420976f,
                                 0.15415067982725836f, 0.11778303565638346f};
  const float* hcur = h0;
  float* houts[NLAYERS] = {hA, hB, hA, nullptr};
  for (int i = 0; i < NLAYERS; i++) {
    k_adj<<<3 * B_DIA * 10, 256, 0, stream>>>(hcur, h0, sim, cross, supb);
    if (i < NLAYERS - 1) {
      k_gemm<1><<<4 * (NNODE / 16), 64, 0, stream>>>(
          supb, Wt + (i + 1) * NDIM * NDIM, nullptr, houts[i], thetas[i]);
      hcur = houts[i];
    } else {
      k_gemm<2><<<4 * (NNODE / 16), 64, 0, stream>>>(
          supb, Wt + (i + 1) * NDIM * NDIM, nullptr, out, thetas[i]);
    }
  }
}

// Round 5
// 180.268 us; speedup vs baseline: 3.5422x; 1.1117x over previous
//
#include <hip/hip_runtime.h>
#include <hip/hip_bf16.h>

#define N_UTT 4000
#define NDIM 256
#define B_DIA 100
#define L_DIA 40
#define NNODE 12000   // 3*N_UTT
#define NLAYERS 4

typedef __attribute__((ext_vector_type(8))) short short8;   // 8 bf16 (4 VGPRs)
typedef __attribute__((ext_vector_type(4))) float f32x4;    // MFMA acc

union bfpk2 { __hip_bfloat16 h[2]; unsigned int u; };
union bfpk4 { __hip_bfloat16 h[4]; uint2 u; };

// ---------------------------------------------------------------------------
// K1: build x = concat(a, v, l + spk_emb[argmax(q)]); write x-part of out,
// x_bf16 (natural), xn_bf16 (normalized). One block per node row.
__global__ void k_build_x(const float* __restrict__ a, const float* __restrict__ v,
                          const float* __restrict__ l, const float* __restrict__ qmask,
                          const float* __restrict__ spk, float* __restrict__ out,
                          __hip_bfloat16* __restrict__ xb,
                          __hip_bfloat16* __restrict__ xnb) {
  int r = blockIdx.x;          // 0..11999
  int t = threadIdx.x;         // 0..255
  int m = r / N_UTT;
  int i = r - m * N_UTT;
  float val;
  if (m == 0) val = a[i * NDIM + t];
  else if (m == 1) val = v[i * NDIM + t];
  else {
    int b = i / L_DIA, p = i - b * L_DIA;
    float q0 = qmask[p * (B_DIA * 2) + b * 2 + 0];
    float q1 = qmask[p * (B_DIA * 2) + b * 2 + 1];
    int s = (q1 > q0) ? 1 : 0;
    val = l[i * NDIM + t] + spk[s * NDIM + t];
  }
  out[i * 1536 + m * 512 + t] = val;           // x-part of final output
  xb[r * NDIM + t] = __float2bfloat16(val);
  float ss = val * val;
  #pragma unroll
  for (int off = 32; off > 0; off >>= 1) ss += __shfl_down(ss, off);
  __shared__ float wsum[4];
  int wid = t >> 6, lane = t & 63;
  if (lane == 0) wsum[wid] = ss;
  __syncthreads();
  float inv = rsqrtf(wsum[0] + wsum[1] + wsum[2] + wsum[3]);
  xnb[r * NDIM + t] = __float2bfloat16(val * inv);
}

// ---------------------------------------------------------------------------
// K2 (fused sim+cross+degree+norm -> A_ext builder):
// one block per dialogue, 192 thr = 3 waves. Wave w = modality m.
// Computes 40x40 angular sim (MFMA), cross-modal diagonal, degree norm, and
// writes A_ext slab [48][256] bf16 for mb = m*100+b:
//   k<40:        S'[row][k]      (0.9*dinv*sim*dinv)
//   k=64+row:    c0'[row]        (cross with partner pm0, normalized)
//   k=128+row:   c1'[row]        (cross with partner pm1)
//   k=192+row:   0.1             (h0 term)
//   else 0.
__global__ void k_graph(const __hip_bfloat16* __restrict__ xn,
                        __hip_bfloat16* __restrict__ Aext) {
  int b = blockIdx.x;           // dialogue
  int t = threadIdx.x;          // 0..191
  int w = t >> 6, l = t & 63;
  int l15 = l & 15, lk = (l >> 4) * 8;
  int m = w;
  int pm = (w + 1) % 3;
  int pairidx = (w == 0) ? 0 : (w == 1) ? 2 : 1;  // (0,1)->0 (1,2)->2 (2,0)->1
  int obase = m * N_UTT + b * L_DIA;
  int pbase = pm * N_UTT + b * L_DIA;
  const short8* xs = (const short8*)xn;

  int rowi[3];
  #pragma unroll
  for (int rt = 0; rt < 3; rt++) {
    int rr_ = 16 * rt + l15;
    rowi[rt] = (rr_ < L_DIA) ? rr_ : (L_DIA - 1);
  }
  f32x4 s[3][3], cacc[3];
  #pragma unroll
  for (int rt = 0; rt < 3; rt++) {
    cacc[rt] = (f32x4){0.f,0.f,0.f,0.f};
    #pragma unroll
    for (int ct = 0; ct < 3; ct++) s[rt][ct] = (f32x4){0.f,0.f,0.f,0.f};
  }
  for (int k0 = 0; k0 < NDIM; k0 += 32) {
    short8 own[3], par[3];
    #pragma unroll
    for (int rt = 0; rt < 3; rt++) own[rt] = xs[((obase + rowi[rt]) * NDIM + k0 + lk) >> 3];
    #pragma unroll
    for (int rt = 0; rt < 3; rt++) par[rt] = xs[((pbase + rowi[rt]) * NDIM + k0 + lk) >> 3];
    #pragma unroll
    for (int rt = 0; rt < 3; rt++) {
      #pragma unroll
      for (int ct = 0; ct < 3; ct++)
        s[rt][ct] = __builtin_amdgcn_mfma_f32_16x16x32_bf16(own[rt], own[ct], s[rt][ct], 0, 0, 0);
      cacc[rt] = __builtin_amdgcn_mfma_f32_16x16x32_bf16(own[rt], par[rt], cacc[rt], 0, 0, 0);
    }
  }
  __shared__ float sim_s[3][L_DIA][41];
  __shared__ float cr_s[3][L_DIA];
  __shared__ float dinv_s[3][L_DIA];
  const float inv_pi = 0.31830988618379067f;
  #pragma unroll
  for (int rt = 0; rt < 3; rt++) {
    #pragma unroll
    for (int ct = 0; ct < 3; ct++) {
      #pragma unroll
      for (int rr = 0; rr < 4; rr++) {
        int row = 16 * rt + (l >> 4) * 4 + rr;
        int col = 16 * ct + l15;
        if (row < L_DIA && col < L_DIA) {
          float cs = fminf(fmaxf(s[rt][ct][rr] * 0.99999f, -1.f), 1.f);
          sim_s[m][row][col] = 1.0f - acosf(cs) * inv_pi;
        }
      }
    }
    #pragma unroll
    for (int rr = 0; rr < 4; rr++) {
      if (l15 == ((l >> 4) * 4 + rr)) {
        int dgi = 16 * rt + l15;
        if (dgi < L_DIA) {
          float cs = fminf(fmaxf(cacc[rt][rr] * 0.99999f, -1.f), 1.f);
          cr_s[pairidx][dgi] = 1.0f - acosf(cs) * inv_pi;
        }
      }
    }
  }
  __syncthreads();
  if (t < 3 * L_DIA) {
    int mm = t / L_DIA, p = t - mm * L_DIA;
    float d = 0.f;
    #pragma unroll 10
    for (int q = 0; q < L_DIA; q++) d += sim_s[mm][p][q];
    if (mm == 0)      d += cr_s[0][p] + cr_s[1][p];
    else if (mm == 1) d += cr_s[0][p] + cr_s[2][p];
    else              d += cr_s[1][p] + cr_s[2][p];
    dinv_s[mm][p] = rsqrtf(d);
  }
  __syncthreads();
  // partner/pair mapping (must match k_layer's src order)
  int pm0, pr0, pm1, pr1;
  if (m == 0)      { pm0 = 1; pr0 = 0; pm1 = 2; pr1 = 1; }
  else if (m == 1) { pm0 = 0; pr0 = 0; pm1 = 2; pr1 = 2; }
  else             { pm0 = 0; pr0 = 1; pm1 = 1; pr1 = 2; }
  int mb = m * B_DIA + b;
  unsigned int* Au = (unsigned int*)Aext;
  // 48 rows x 256 cols bf16 = 48*128 uints
  for (int e = l; e < 48 * 128; e += 64) {
    int row = e >> 7;
    int kp = (e & 127) * 2;
    bfpk2 pk; pk.u = 0;
    if (row < L_DIA) {
      #pragma unroll
      for (int jj = 0; jj < 2; jj++) {
        int k = kp + jj;
        float v = 0.f;
        if (k < L_DIA) {
          v = 0.9f * sim_s[m][row][k] * dinv_s[m][row] * dinv_s[m][k];
        } else if (k - 64 == row) {
          v = 0.9f * cr_s[pr0][row] * dinv_s[m][row] * dinv_s[pm0][row];
        } else if (k - 128 == row) {
          v = 0.9f * cr_s[pr1][row] * dinv_s[m][row] * dinv_s[pm1][row];
        } else if (k - 192 == row) {
          v = 0.1f;
        }
        pk.h[jj] = __float2bfloat16(v);
      }
    }
    Au[(mb * 48 + row) * 128 + (e & 127)] = pk.u;
  }
}

// ---------------------------------------------------------------------------
// K3: weight transpose+bf16 via LDS tile: Wt[g][n][k] = W_g[k][n]
__global__ void k_wt(const float* __restrict__ W0, const float* __restrict__ Wc,
                     __hip_bfloat16* __restrict__ Wt) {
  int k0 = blockIdx.x * 64, n0 = blockIdx.y * 64, g = blockIdx.z;
  int t = threadIdx.x;
  const float* src = (g == 0) ? W0 : (Wc + (g - 1) * NDIM * NDIM);
  __shared__ float tile[64][65];
  #pragma unroll
  for (int it = 0; it < 16; it++) {
    int e = t + 256 * it;
    int row = e >> 6, col = e & 63;
    tile[row][col] = src[(k0 + row) * NDIM + n0 + col];
  }
  __syncthreads();
  #pragma unroll
  for (int it = 0; it < 16; it++) {
    int e = t + 256 * it;
    int row = e >> 6, col = e & 63;
    Wt[(g * NDIM + n0 + row) * NDIM + k0 + col] = __float2bfloat16(tile[col][row]);
  }
}

// ---------------------------------------------------------------------------
// K4: h0 GEMM: h0_t[mb][col][p] = relu(xb @ W0 + b0), stored TRANSPOSED
// per dialogue. One wave per block: 16 rows x 64 cols.
__global__ void k_gemm0(const __hip_bfloat16* __restrict__ A,
                        const __hip_bfloat16* __restrict__ Wt,
                        const float* __restrict__ bias,
                        __hip_bfloat16* __restrict__ h0t) {
  int rt = blockIdx.x >> 2;       // row tile 0..749
  int ch = blockIdx.x & 3;        // col quarter
  int l = threadIdx.x;            // 0..63
  int l15 = l & 15, lk = (l >> 4) * 8;
  int row = rt * 16 + l15;
  const short8* As = (const short8*)A;
  const short8* Bs = (const short8*)Wt;
  f32x4 acc[4];
  #pragma unroll
  for (int c = 0; c < 4; c++) acc[c] = (f32x4){0.f,0.f,0.f,0.f};
  #pragma unroll
  for (int k0 = 0; k0 < NDIM; k0 += 32) {
    short8 af = As[(row * NDIM + k0 + lk) >> 3];
    #pragma unroll
    for (int c = 0; c < 4; c++) {
      int col = ch * 64 + c * 16 + l15;
      short8 bf = Bs[(col * NDIM + k0 + lk) >> 3];
      acc[c] = __builtin_amdgcn_mfma_f32_16x16x32_bf16(af, bf, acc[c], 0, 0, 0);
    }
  }
  int node0 = rt * 16 + (l >> 4) * 4;   // 4-row group, never straddles dialogue
  int m = node0 / N_UTT;
  int i = node0 - m * N_UTT;
  int b = i / L_DIA, p0 = i - b * L_DIA;
  int mb = m * B_DIA + b;
  #pragma unroll
  for (int c = 0; c < 4; c++) {
    int col = ch * 64 + c * 16 + l15;
    bfpk4 pk;
    #pragma unroll
    for (int rr = 0; rr < 4; rr++)
      pk.h[rr] = __float2bfloat16(fmaxf(acc[c][rr] + bias[col], 0.f));
    *(uint2*)&h0t[((mb * NDIM + col) << 6) + p0] = pk.u;
  }
}

// ---------------------------------------------------------------------------
// K5: fused layer: sup = A_ext @ [h_m; h_pm0; h_pm1; h0] (K=256 MFMA),
// then h_next = relu(theta*(sup@W) + (1-theta)*sup).
// One block per (m,b): 256 thr = 4 waves; wave w owns cols [64w, 64w+64).
// LAST=0: writes ht_out (transposed slab); LAST=1: writes out h-slots (fp32).
template<int LAST>
__global__ __launch_bounds__(256) void k_layer(
    const __hip_bfloat16* __restrict__ ht_in,   // [300][256][64]
    const __hip_bfloat16* __restrict__ h0t,     // [300][256][64]
    const __hip_bfloat16* __restrict__ Aext,    // [300][48][256]
    const __hip_bfloat16* __restrict__ Wt,      // layer's [256][256]
    __hip_bfloat16* __restrict__ ht_out,
    float* __restrict__ out, float theta) {
  int mb = blockIdx.x;
  int m = mb / B_DIA, b = mb - m * B_DIA;
  int t = threadIdx.x, w = t >> 6, l = t & 63;
  int l15 = l & 15, lk = (l >> 4) * 8;
  int pm0, pm1;
  if (m == 0)      { pm0 = 1; pm1 = 2; }
  else if (m == 1) { pm0 = 0; pm1 = 2; }
  else             { pm0 = 0; pm1 = 1; }
  const __hip_bfloat16* srcs[4] = {
    ht_in + ((m   * B_DIA + b) << 14),
    ht_in + ((pm0 * B_DIA + b) << 14),
    ht_in + ((pm1 * B_DIA + b) << 14),
    h0t   + ((m   * B_DIA + b) << 14) };
  const short8* A8 = (const short8*)Aext;

  // ---- stage 1: sup = A_ext @ B_ext ----
  f32x4 acc[3][4];
  #pragma unroll
  for (int rt = 0; rt < 3; rt++)
    #pragma unroll
    for (int c = 0; c < 4; c++) acc[rt][c] = (f32x4){0.f,0.f,0.f,0.f};
  #pragma unroll
  for (int j = 0; j < 8; j++) {          // k0 = 32*j; source block j>>1
    int k32 = (j & 1) * 32;
    short8 a[3];
    #pragma unroll
    for (int rt = 0; rt < 3; rt++)
      a[rt] = A8[((mb * 48 + rt * 16 + l15) * 256 + j * 32 + lk) >> 3];
    const short8* bp = (const short8*)srcs[j >> 1];
    #pragma unroll
    for (int c = 0; c < 4; c++) {
      int col = w * 64 + c * 16 + l15;
      short8 bf = bp[((col << 6) + k32 + lk) >> 3];
      #pragma unroll
      for (int rt = 0; rt < 3; rt++)
        acc[rt][c] = __builtin_amdgcn_mfma_f32_16x16x32_bf16(a[rt], bf, acc[rt][c], 0, 0, 0);
    }
  }
  __shared__ alignas(16) __hip_bfloat16 sup[48][264];
  #pragma unroll
  for (int rt = 0; rt < 3; rt++) {
    #pragma unroll
    for (int c = 0; c < 4; c++) {
      int col = w * 64 + c * 16 + l15;
      #pragma unroll
      for (int rr = 0; rr < 4; rr++) {
        int row = rt * 16 + (l >> 4) * 4 + rr;
        sup[row][col] = __float2bfloat16(acc[rt][c][rr]);
      }
    }
  }
  __syncthreads();

  // ---- stage 2: o = sup @ W ----
  f32x4 o[3][4];
  #pragma unroll
  for (int rt = 0; rt < 3; rt++)
    #pragma unroll
    for (int c = 0; c < 4; c++) o[rt][c] = (f32x4){0.f,0.f,0.f,0.f};
  #pragma unroll
  for (int k0 = 0; k0 < NDIM; k0 += 32) {
    short8 a[3];
    #pragma unroll
    for (int rt = 0; rt < 3; rt++)
      a[rt] = *(const short8*)&sup[rt * 16 + l15][k0 + lk];
    #pragma unroll
    for (int c = 0; c < 4; c++) {
      int col = w * 64 + c * 16 + l15;
      short8 bf = *(const short8*)&Wt[col * NDIM + k0 + lk];
      #pragma unroll
      for (int rt = 0; rt < 3; rt++)
        o[rt][c] = __builtin_amdgcn_mfma_f32_16x16x32_bf16(a[rt], bf, o[rt][c], 0, 0, 0);
    }
  }
  float onemt = 1.f - theta;
  #pragma unroll
  for (int rt = 0; rt < 3; rt++) {
    int p0 = rt * 16 + (l >> 4) * 4;
    if (p0 >= L_DIA) continue;
    #pragma unroll
    for (int c = 0; c < 4; c++) {
      int col = w * 64 + c * 16 + l15;
      float vv[4];
      #pragma unroll
      for (int rr = 0; rr < 4; rr++) {
        float supv = __bfloat162float(sup[p0 + rr][col]);
        vv[rr] = fmaxf(theta * o[rt][c][rr] + onemt * supv, 0.f);
      }
      if (LAST) {
        #pragma unroll
        for (int rr = 0; rr < 4; rr++)
          out[(b * L_DIA + p0 + rr) * 1536 + m * 512 + 256 + col] = vv[rr];
      } else {
        bfpk4 pk;
        #pragma unroll
        for (int rr = 0; rr < 4; rr++) pk.h[rr] = __float2bfloat16(vv[rr]);
        *(uint2*)&ht_out[((mb * NDIM + col) << 6) + p0] = pk.u;
      }
    }
  }
}

// ---------------------------------------------------------------------------
extern "C" void kernel_launch(void* const* d_in, const int* in_sizes, int n_in,
                              void* d_out, int out_size, void* d_ws, size_t ws_size,
                              hipStream_t stream) {
  const float* a     = (const float*)d_in[0];
  const float* v     = (const float*)d_in[1];
  const float* l     = (const float*)d_in[2];
  const float* qmask = (const float*)d_in[3];
  const float* spk   = (const float*)d_in[4];
  const float* W0    = (const float*)d_in[5];
  const float* b0    = (const float*)d_in[6];
  const float* Wc    = (const float*)d_in[7];
  float* out = (float*)d_out;
  float* ws  = (float*)d_ws;

  __hip_bfloat16* xb   = (__hip_bfloat16*)ws;                    // 1,536,000 fl
  __hip_bfloat16* xnb  = (__hip_bfloat16*)(ws + 1536000);        // 1,536,000
  __hip_bfloat16* h0t  = (__hip_bfloat16*)(ws + 3072000);        // 2,457,600
  __hip_bfloat16* htA  = (__hip_bfloat16*)(ws + 5529600);        // 2,457,600
  __hip_bfloat16* htB  = (__hip_bfloat16*)(ws + 7987200);        // 2,457,600
  __hip_bfloat16* Aext = (__hip_bfloat16*)(ws + 10444800);       // 1,843,200
  __hip_bfloat16* Wt   = (__hip_bfloat16*)(ws + 12288000);       //   163,840
  // total 12,451,840 fl = 49.8 MB

  k_wt<<<dim3(4, 4, 5), 256, 0, stream>>>(W0, Wc, Wt);
  k_build_x<<<NNODE, 256, 0, stream>>>(a, v, l, qmask, spk, out, xb, xnb);
  k_graph<<<B_DIA, 192, 0, stream>>>(xnb, Aext);
  k_gemm0<<<4 * (NNODE / 16), 64, 0, stream>>>(xb, Wt, b0, h0t);

  const float thetas[NLAYERS] = {0.40546510810816438f, 0.22314355131420976f,
                                 0.15415067982725836f, 0.11778303565638346f};
  const __hip_bfloat16* hcur = h0t;
  __hip_bfloat16* houts[NLAYERS] = {htA, htB, htA, nullptr};
  for (int i = 0; i < NLAYERS; i++) {
    if (i < NLAYERS - 1) {
      k_layer<0><<<3 * B_DIA, 256, 0, stream>>>(
          hcur, h0t, Aext, Wt + (i + 1) * NDIM * NDIM, houts[i], nullptr, thetas[i]);
      hcur = houts[i];
    } else {
      k_layer<1><<<3 * B_DIA, 256, 0, stream>>>(
          hcur, h0t, Aext, Wt + (i + 1) * NDIM * NDIM, nullptr, out, thetas[i]);
    }
  }
}